// Round 1
// baseline (168.872 us; speedup 1.0000x reference)
//
#include <hip/hip_runtime.h>
#include <hip/hip_bf16.h>

typedef __attribute__((ext_vector_type(8)))  __bf16 bf16x8;
typedef __attribute__((ext_vector_type(4)))  __bf16 bf16x4;
typedef __attribute__((ext_vector_type(16))) float  f32x16;

namespace {
constexpr int kB  = 16;
constexpr int kSQ = 2048;
constexpr int kSK = 2048;
constexpr int kD  = 64;
constexpr int kQB = 32;               // q-rows per workgroup
constexpr int kNW = 8;                // waves per workgroup
constexpr int kKPW = kSK / kNW;       // 256 keys per wave in pass 1
constexpr int kLdsP = kQB * kSK * 2;  // 131072 B (P tile, bf16, swizzled)
constexpr int kLdsTot = kLdsP + kNW * kQB * 4; // + row-sum partials
constexpr float kScaleLog2e = 0.18033688011112042f; // (1/8)*log2(e)
}

// One wg = (batch b, 32 q-rows). Pass 1: S=QK^T via bf16 MFMA, mask, exp,
// unnormalized P -> swizzled LDS (bf16), per-row sums. Pass 2a: attn = P/l
// coalesced f32 writes. Pass 2b: PV via MFMA (A from LDS, B=V from L2),
// cross-wave reduce in LDS (reusing P region), scale by 1/l, write ctx.
__global__ __launch_bounds__(512, 2)
void sdpa_fused(const float* __restrict__ Qg, const float* __restrict__ Kg,
                const float* __restrict__ Vg, const int* __restrict__ Mg,
                float* __restrict__ ctxOut, float* __restrict__ attnOut)
{
  __shared__ __align__(16) char lds[kLdsTot];
  float* sums  = reinterpret_cast<float*>(lds + kLdsP); // [8][32] row-sum partials
  float* cpart = reinterpret_cast<float*>(lds);         // reuse of P region later

  const int tid  = threadIdx.x;
  const int wid  = tid >> 6;
  const int lane = tid & 63;
  const int l31  = lane & 31;
  const int lh   = lane >> 5;

  // XCD-aware bijective swizzle: 1024 wgs, 128 contiguous per XCD (2 batches).
  const int wg = (blockIdx.x & 7) * 128 + (blockIdx.x >> 3);
  const int b  = wg >> 6;            // 64 q-blocks per batch
  const int q0 = (wg & 63) * kQB;

  const float* Qb = Qg + (size_t)b * kSQ * kD;
  const float* Kb = Kg + (size_t)b * kSK * kD;
  const float* Vb = Vg + (size_t)b * kSK * kD;
  const int*   Mb = Mg + (size_t)b * kSQ * kSK;

  // ---- Q fragments (A operand of 32x32x16: row = lane&31, k = (lane>>5)*8+e)
  bf16x8 qf[4];
  {
    const float* qp = Qb + (q0 + l31) * kD + lh * 8;
#pragma unroll
    for (int s = 0; s < 4; ++s) {
#pragma unroll
      for (int e = 0; e < 8; ++e) qf[s][e] = (__bf16)qp[s * 16 + e];
    }
  }

  // ---- pass 1 ----
  float lsum[16];
#pragma unroll
  for (int r = 0; r < 16; ++r) lsum[r] = 0.f;

  const int kbase = wid * kKPW;
  for (int kt = 0; kt < kKPW / 32; ++kt) {
    const int k0 = kbase + kt * 32;
    f32x16 acc;
#pragma unroll
    for (int r = 0; r < 16; ++r) acc[r] = 0.f;
    const float* kp = Kb + (k0 + l31) * kD + lh * 8;
#pragma unroll
    for (int s = 0; s < 4; ++s) {
      bf16x8 kf;
#pragma unroll
      for (int e = 0; e < 8; ++e) kf[e] = (__bf16)kp[s * 16 + e];
      acc = __builtin_amdgcn_mfma_f32_32x32x16_bf16(qf[s], kf, acc, 0, 0, 0);
    }
    // C/D layout: col = lane&31, row = (r&3) + 8*(r>>2) + 4*(lane>>5)
    const int col = k0 + l31;
    const int* mp = Mb + (size_t)q0 * kSK + col;
#pragma unroll
    for (int r = 0; r < 16; ++r) {
      const int row = (r & 3) + 8 * (r >> 2) + 4 * lh;
      const int mv  = mp[row * kSK];                 // mask TRUE -> excluded
      const float pv = mv ? 0.f : exp2f(acc[r] * kScaleLog2e);
      lsum[r] += pv;
      const int byte = ((row << 12) + (col << 1)) ^ ((row & 7) << 4); // swizzle
      *reinterpret_cast<__bf16*>(lds + byte) = (__bf16)pv;
    }
  }

  // ---- row-sum reduction: each 32-lane half owns disjoint rows ----
#pragma unroll
  for (int m = 1; m < 32; m <<= 1) {
#pragma unroll
    for (int r = 0; r < 16; ++r) lsum[r] += __shfl_xor(lsum[r], m, 64);
  }
  if (l31 == 0) {
#pragma unroll
    for (int r = 0; r < 16; ++r) {
      const int row = (r & 3) + 8 * (r >> 2) + 4 * lh;
      sums[wid * kQB + row] = lsum[r];
    }
  }
  __syncthreads();

  // ---- pass 2a: attn = P / l (wave owns 4 q-rows, coalesced f32x4 stores)
#pragma unroll
  for (int rr = 0; rr < 4; ++rr) {
    const int row = wid * 4 + rr;
    float l = 0.f;
#pragma unroll
    for (int w = 0; w < kNW; ++w) l += sums[w * kQB + row];
    const float inv = 1.0f / l;
    const int xorm = (row & 7) << 4;
    float* arow = attnOut + ((size_t)b * kSQ + q0 + row) * kSK;
    for (int c0 = lane * 4; c0 < kSK; c0 += 256) {
      const int byte = ((row << 12) + (c0 << 1)) ^ xorm;
      const bf16x4 p4 = *reinterpret_cast<const bf16x4*>(lds + byte);
      float4 o;
      o.x = (float)p4[0] * inv;
      o.y = (float)p4[1] * inv;
      o.z = (float)p4[2] * inv;
      o.w = (float)p4[3] * inv;
      *reinterpret_cast<float4*>(arow + c0) = o;
    }
  }

  // ---- pass 2b: PV. Waves 0-3 -> d 0..31, waves 4-7 -> d 32..63; each over
  // a 512-key range; acc = sum_k P[m][k] * V[k][d].
  const int d0  = (wid >> 2) * 32;
  const int kb2 = (wid & 3) * 512;
  f32x16 cacc;
#pragma unroll
  for (int r = 0; r < 16; ++r) cacc[r] = 0.f;
  for (int ks = 0; ks < 512 / 16; ++ks) {
    const int k0 = kb2 + ks * 16;
    const int abyte = ((l31 << 12) + ((k0 + lh * 8) << 1)) ^ ((l31 & 7) << 4);
    const bf16x8 af = *reinterpret_cast<const bf16x8*>(lds + abyte);
    bf16x8 vf;  // B layout: n = lane&31 (=d), k = (lane>>5)*8+e
    const float* vp = Vb + (size_t)(k0 + lh * 8) * kD + d0 + l31;
#pragma unroll
    for (int e = 0; e < 8; ++e) vf[e] = (__bf16)vp[e * kD];
    cacc = __builtin_amdgcn_mfma_f32_32x32x16_bf16(af, vf, cacc, 0, 0, 0);
  }
  __syncthreads();  // all P reads done; P region reused for ctx partials

#pragma unroll
  for (int r = 0; r < 16; ++r) {
    const int row = (r & 3) + 8 * (r >> 2) + 4 * lh;
    cpart[wid * (kQB * 32) + row * 32 + l31] = cacc[r];
  }
  __syncthreads();

  // ---- final: reduce 4 partials per d-half, scale by 1/l, write ctx ----
  {
    const int m = tid >> 4;           // 0..31
    const int c = (tid & 15) * 4;     // 0..60
    const int team = (c >= 32) ? 4 : 0;
    const int cc = c & 31;
    float4 o = make_float4(0.f, 0.f, 0.f, 0.f);
#pragma unroll
    for (int w = 0; w < 4; ++w) {
      const float4 pv = *reinterpret_cast<const float4*>(
          cpart + (team + w) * (kQB * 32) + m * 32 + cc);
      o.x += pv.x; o.y += pv.y; o.z += pv.z; o.w += pv.w;
    }
    float l = 0.f;
#pragma unroll
    for (int w = 0; w < kNW; ++w) l += sums[w * kQB + m];
    const float inv = 1.0f / l;
    o.x *= inv; o.y *= inv; o.z *= inv; o.w *= inv;
    *reinterpret_cast<float4*>(ctxOut + ((size_t)b * kSQ + q0 + m) * kD + c) = o;
  }
}

extern "C" void kernel_launch(void* const* d_in, const int* in_sizes, int n_in,
                              void* d_out, int out_size, void* d_ws, size_t ws_size,
                              hipStream_t stream)
{
  const float* Q = (const float*)d_in[0];
  const float* K = (const float*)d_in[1];
  const float* V = (const float*)d_in[2];
  const int*   M = (const int*)d_in[3];   // bool mask pushed as 4-byte words
  float* ctx  = (float*)d_out;
  float* attn = (float*)d_out + (size_t)kB * kSQ * kD;

  dim3 grid(kB * (kSQ / kQB));  // 1024
  dim3 block(512);
  hipLaunchKernelGGL(sdpa_fused, grid, block, 0, stream, Q, K, V, M, ctx, attn);
}